// Round 2
// baseline (1035.695 us; speedup 1.0000x reference)
//
#include <hip/hip_runtime.h>
#include <cmath>

#define EPS_BN 1e-5f
#define EPS_SM 1e-16f
#define NEG_INF (-INFINITY)

typedef _Float16 h2f __attribute__((ext_vector_type(2)));

#if defined(__has_builtin)
#if __has_builtin(__builtin_amdgcn_fdot2)
#define DOT2(a, b, c) __builtin_amdgcn_fdot2((a), (b), (c), false)
#endif
#endif
#ifndef DOT2
#define DOT2(a, b, c) ((c) + (float)(a).x * (float)(b).x + (float)(a).y * (float)(b).y)
#endif

// ============================ utility: zero fill ============================
__global__ void zero_kernel(int* __restrict__ p, int n) {
    int i = blockIdx.x * 256 + threadIdx.x;
    if (i < n) p[i] = 0;
}

// ============================ CSR build ============================
__global__ void hist_kernel(const int* __restrict__ edst, int* __restrict__ deg, int E) {
    int e = blockIdx.x * 256 + threadIdx.x;
    if (e < E) atomicAdd(&deg[edst[e]], 1);
}

__global__ void scan1_kernel(const int* __restrict__ deg, int* __restrict__ row_ptr,
                             int* __restrict__ bsum, int N) {
    __shared__ int s[256];
    int t = threadIdx.x;
    int i = blockIdx.x * 256 + t;
    int v = (i < N) ? deg[i] : 0;
    s[t] = v; __syncthreads();
    for (int off = 1; off < 256; off <<= 1) {
        int x = (t >= off) ? s[t - off] : 0;
        __syncthreads();
        s[t] += x;
        __syncthreads();
    }
    if (i < N) row_ptr[i] = s[t] - v;   // exclusive partial
    if (t == 255) bsum[blockIdx.x] = s[t];
}

__global__ void scan2_kernel(int* __restrict__ bsum, int nb) {
    __shared__ int s[1024];
    int t = threadIdx.x;
    int v = (t < nb) ? bsum[t] : 0;
    s[t] = v; __syncthreads();
    for (int off = 1; off < 1024; off <<= 1) {
        int x = (t >= off) ? s[t - off] : 0;
        __syncthreads();
        s[t] += x;
        __syncthreads();
    }
    if (t < nb) bsum[t] = s[t] - v;     // exclusive
}

__global__ void scan3_kernel(int* __restrict__ row_ptr, int* __restrict__ cursor,
                             const int* __restrict__ bsum, int N, int E) {
    int i = blockIdx.x * 256 + threadIdx.x;
    if (i < N) {
        int v = row_ptr[i] + bsum[blockIdx.x];
        row_ptr[i] = v;
        cursor[i] = v;
    } else if (i == N) {
        row_ptr[N] = E;
    }
}

__global__ void scatter_kernel(const int* __restrict__ edst, int* __restrict__ cursor,
                               int* __restrict__ eid, int E) {
    int e = blockIdx.x * 256 + threadIdx.x;
    if (e < E) {
        int p = atomicAdd(&cursor[edst[e]], 1);
        eid[p] = e;
    }
}

// graph ranges by binary search (batch is sorted)
__global__ void gptr_kernel(const int* __restrict__ batch, int* __restrict__ gptr, int N, int G) {
    int g = blockIdx.x * 256 + threadIdx.x;
    if (g > G) return;
    int lo = 0, hi = N;
    while (lo < hi) { int mid = (lo + hi) >> 1; if (batch[mid] < g) lo = mid + 1; else hi = mid; }
    gptr[g] = lo;
}

// ============================ input projection ============================
// h = relu(x @ lin_w + lin_b); x[N,32], lin_w[32,64]
__global__ void proj_kernel(const float* __restrict__ x, const float* __restrict__ lin_w,
                            const float* __restrict__ lin_b, float* __restrict__ h, int N) {
    __shared__ float Xs[64 * 32];
    int t = threadIdx.x;
    int col = t & 63, sub = t >> 6;
    float w[32];
#pragma unroll
    for (int k = 0; k < 32; k++) w[k] = lin_w[k * 64 + col];
    float b = lin_b[col];
    int r0 = blockIdx.x * 64;
    const float4* xg = (const float4*)(x + (size_t)r0 * 32);
    float4* Xs4 = (float4*)Xs;
    size_t totf4 = (size_t)N * 8;   // N rows * 32 floats / 4
#pragma unroll
    for (int i = 0; i < 2; i++) {
        int idx = t + i * 256;
        size_t gidx = (size_t)r0 * 8 + idx;
        Xs4[idx] = (gidx < totf4) ? xg[idx] : make_float4(0.f, 0.f, 0.f, 0.f);
    }
    __syncthreads();
    for (int rr = sub; rr < 64; rr += 4) {
        int r = r0 + rr;
        if (r >= N) break;
        float acc = b;
        const float4* a4p = (const float4*)(Xs + rr * 32);
#pragma unroll
        for (int kk = 0; kk < 8; kk++) {
            float4 a4 = a4p[kk];
            acc += a4.x * w[kk * 4] + a4.y * w[kk * 4 + 1] + a4.z * w[kk * 4 + 2] + a4.w * w[kk * 4 + 3];
        }
        h[(size_t)r * 64 + col] = fmaxf(acc, 0.f);
    }
}

// ============================ BN stats ============================
__global__ void bn_stats_kernel(const float* __restrict__ h, float* __restrict__ bnacc, int N) {
    __shared__ float ls[256], lq[256];
    int t = threadIdx.x, c = t & 63, sub = t >> 6;
    int r0 = blockIdx.x * 512;
    int rend = min(r0 + 512, N);
    float s = 0.f, q = 0.f;
    for (int r = r0 + sub; r < rend; r += 4) {
        float v = h[(size_t)r * 64 + c];
        s += v; q += v * v;
    }
    ls[t] = s; lq[t] = q;
    __syncthreads();
    if (t < 64) {
        float S = ls[t] + ls[t + 64] + ls[t + 128] + ls[t + 192];
        float Qv = lq[t] + lq[t + 64] + lq[t + 128] + lq[t + 192];
        atomicAdd(&bnacc[t], S);
        atomicAdd(&bnacc[64 + t], Qv);
    }
}

// ============================ fold BN + attention vectors into weights ============================
// Wp[64,256] = scl[k]*W[k,j];  bpb[256] = sum_k sft[k]*W[k,j]
// P[64,8]: cols 0..3 = sum_c Wp[k, h*64+c]*att_src[h,c]; cols 4..7 same with att_dst
// cs[8]  : same folds applied to bpb
// Q[8,4] : Q[f,h] = sum_c conv_we[f, h*64+c]*att_edge[h,c]
// Wfh2[p=0..127][col]: half2 of Wf[2p][col],Wf[2p+1][col], where Wf[j][col] =
//   0.25 * Wp[(j>>2)*256 + (j&3)*64 + col]   (agg row position j = c*4 + h)
__global__ void fold_kernel(const float* __restrict__ bnacc,
                            const float* __restrict__ gamma, const float* __restrict__ beta,
                            const float* __restrict__ convw, const float* __restrict__ convwe,
                            const float* __restrict__ atts, const float* __restrict__ attd,
                            const float* __restrict__ atte,
                            float* __restrict__ Wp, float* __restrict__ bpb,
                            float* __restrict__ P, float* __restrict__ cs, float* __restrict__ Qm,
                            h2f* __restrict__ Wfh2,
                            float invN) {
    __shared__ float scl[64], sft[64];
    int t = threadIdx.x;
    if (t < 64) {
        float mu = bnacc[t] * invN;
        float var = bnacc[64 + t] * invN - mu * mu;
        var = fmaxf(var, 0.f);
        float sc = gamma[t] / sqrtf(var + EPS_BN);
        scl[t] = sc;
        sft[t] = beta[t] - mu * sc;
    }
    __syncthreads();
    {
        float bacc = 0.f;
        for (int k = 0; k < 64; k++) {
            float wv = convw[k * 256 + t];
            Wp[k * 256 + t] = scl[k] * wv;
            bacc += sft[k] * wv;
        }
        bpb[t] = bacc;
    }
    __syncthreads();
    for (int idx = t; idx < 512; idx += 256) {
        int k = idx >> 3, o = idx & 7, hh = o & 3;
        const float* av = (o < 4) ? atts : attd;
        float acc = 0.f;
        for (int c = 0; c < 64; c++) acc += Wp[k * 256 + hh * 64 + c] * av[hh * 64 + c];
        P[idx] = acc;
    }
    for (int i = t; i < 8192; i += 256) {
        int p = i >> 6, col = i & 63;
        int j0 = 2 * p, j1 = 2 * p + 1;
        h2f wv;
        wv.x = (_Float16)(Wp[(j0 >> 2) * 256 + (j0 & 3) * 64 + col] * 0.25f);
        wv.y = (_Float16)(Wp[(j1 >> 2) * 256 + (j1 & 3) * 64 + col] * 0.25f);
        Wfh2[p * 64 + col] = wv;
    }
    if (t < 8) {
        int hh = t & 3;
        const float* av = (t < 4) ? atts : attd;
        float acc = 0.f;
        for (int c = 0; c < 64; c++) acc += bpb[hh * 64 + c] * av[hh * 64 + c];
        cs[t] = acc;
    }
    if (t < 32) {
        int f = t >> 2, hh = t & 3;
        float acc = 0.f;
        for (int c = 0; c < 64; c++) acc += convwe[f * 256 + hh * 64 + c] * atte[hh * 64 + c];
        Qm[t] = acc;
    }
}

// ============================ per-node attention logits: a_sd = h @ P + cs ============================
__global__ void att_node_kernel(const float* __restrict__ h, const float* __restrict__ P,
                                const float* __restrict__ cs, float* __restrict__ a_sd, int N) {
    __shared__ float As[32 * 64];
    __shared__ float Ps[512];
    __shared__ float css[8];
    int t = threadIdx.x;
    int r0 = blockIdx.x * 32;
    const float4* hg = (const float4*)(h + (size_t)r0 * 64);
    float4* As4 = (float4*)As;
    size_t totf4 = (size_t)N * 16;
#pragma unroll
    for (int i = 0; i < 2; i++) {
        int idx = t + i * 256;
        size_t gidx = (size_t)r0 * 16 + idx;
        As4[idx] = (gidx < totf4) ? hg[idx] : make_float4(0.f, 0.f, 0.f, 0.f);
    }
    Ps[t] = P[t];
    Ps[t + 256] = P[t + 256];
    if (t < 8) css[t] = cs[t];
    __syncthreads();
    int row = t >> 3, o = t & 7;
    int rg = r0 + row;
    if (rg >= N) return;
    float acc = css[o];
#pragma unroll 8
    for (int k = 0; k < 64; k++) acc += As[row * 64 + k] * Ps[k * 8 + o];
    a_sd[(size_t)rg * 8 + o] = acc;
}

// ============================ per-edge attention logits: a_e = edge_attr @ Q ============================
__global__ void edge_score_kernel(const float* __restrict__ edge_attr, const float* __restrict__ Qm,
                                  float* __restrict__ a_e, int E) {
    int e = blockIdx.x * 256 + threadIdx.x;
    if (e >= E) return;
    float4 ea0 = ((const float4*)edge_attr)[(size_t)e * 2];
    float4 ea1 = ((const float4*)edge_attr)[(size_t)e * 2 + 1];
    float4 r;
    float* rp = (float*)&r;
#pragma unroll
    for (int hh = 0; hh < 4; hh++) {
        rp[hh] = ea0.x * Qm[0 * 4 + hh] + ea0.y * Qm[1 * 4 + hh] + ea0.z * Qm[2 * 4 + hh] + ea0.w * Qm[3 * 4 + hh]
               + ea1.x * Qm[4 * 4 + hh] + ea1.y * Qm[5 * 4 + hh] + ea1.z * Qm[6 * 4 + hh] + ea1.w * Qm[7 * 4 + hh];
    }
    ((float4*)a_e)[e] = r;
}

// ============================ fused segment softmax + h-aggregation ============================
// one wave per destination node; lane = channel of h; online softmax over CSR edge list.
// Output: agg[n][c*4+h] = (sum_e alpha_h[e] h[src_e][c]) fp16, salpha[n][h] = sum_e alpha_h[e]
__global__ void edge_msg_kernel(const int* __restrict__ row_ptr, const int* __restrict__ eid,
                                const int* __restrict__ esrc,
                                const float* __restrict__ a_sd, const float* __restrict__ a_e,
                                const float* __restrict__ h,
                                _Float16* __restrict__ agg, float* __restrict__ salpha, int N) {
    int lane = threadIdx.x & 63;
    int n = blockIdx.x * 4 + (threadIdx.x >> 6);
    if (n >= N) return;
    int p0 = row_ptr[n], p1 = row_ptr[n + 1];
    int hsel = lane & 3;
    float m0 = NEG_INF, m1 = NEG_INF, m2 = NEG_INF, m3 = NEG_INF;
    float d0 = 0.f, d1 = 0.f, d2 = 0.f, d3 = 0.f;
    float A0 = 0.f, A1 = 0.f, A2 = 0.f, A3 = 0.f;

    for (int pos = p0; pos < p1; pos += 16) {
        int cnt = min(16, p1 - pos);
        float s = NEG_INF;
        int msrc = 0;
        if (lane < cnt * 4) {
            int e = eid[pos + (lane >> 2)];
            int src = esrc[e];
            msrc = src;
            float sc = a_sd[(size_t)src * 8 + hsel] + a_sd[(size_t)n * 8 + 4 + hsel] + a_e[(size_t)e * 4 + hsel];
            s = sc > 0.f ? sc : 0.2f * sc;
        }
        // per-head chunk max (lanes with equal lane&3 form groups under xor {4,8,16,32})
        float cm = s;
        cm = fmaxf(cm, __shfl_xor(cm, 4));
        cm = fmaxf(cm, __shfl_xor(cm, 8));
        cm = fmaxf(cm, __shfl_xor(cm, 16));
        cm = fmaxf(cm, __shfl_xor(cm, 32));
        float nm0 = fmaxf(m0, __shfl(cm, 0));
        float nm1 = fmaxf(m1, __shfl(cm, 1));
        float nm2 = fmaxf(m2, __shfl(cm, 2));
        float nm3 = fmaxf(m3, __shfl(cm, 3));
        float r0s = expf(m0 - nm0), r1s = expf(m1 - nm1), r2s = expf(m2 - nm2), r3s = expf(m3 - nm3);
        d0 *= r0s; A0 *= r0s; m0 = nm0;
        d1 *= r1s; A1 *= r1s; m1 = nm1;
        d2 *= r2s; A2 *= r2s; m2 = nm2;
        d3 *= r3s; A3 *= r3s; m3 = nm3;
        float nmh = hsel == 0 ? nm0 : hsel == 1 ? nm1 : hsel == 2 ? nm2 : nm3;
        float ex = (lane < cnt * 4) ? expf(s - nmh) : 0.f;
        float ds = ex;
        ds += __shfl_xor(ds, 4);
        ds += __shfl_xor(ds, 8);
        ds += __shfl_xor(ds, 16);
        ds += __shfl_xor(ds, 32);
        d0 += __shfl(ds, 0);
        d1 += __shfl(ds, 1);
        d2 += __shfl(ds, 2);
        d3 += __shfl(ds, 3);
        for (int i = 0; i < cnt; i++) {
            int src_i = __shfl(msrc, i * 4);
            float w0 = __shfl(ex, i * 4 + 0);
            float w1 = __shfl(ex, i * 4 + 1);
            float w2 = __shfl(ex, i * 4 + 2);
            float w3 = __shfl(ex, i * 4 + 3);
            float hv = h[(size_t)src_i * 64 + lane];
            A0 += w0 * hv;
            A1 += w1 * hv;
            A2 += w2 * hv;
            A3 += w3 * hv;
        }
    }
    float i0 = 1.f / (d0 + EPS_SM), i1 = 1.f / (d1 + EPS_SM);
    float i2 = 1.f / (d2 + EPS_SM), i3 = 1.f / (d3 + EPS_SM);
    union { h2f v[2]; float2 f; } u;
    u.v[0].x = (_Float16)(A0 * i0);
    u.v[0].y = (_Float16)(A1 * i1);
    u.v[1].x = (_Float16)(A2 * i2);
    u.v[1].y = (_Float16)(A3 * i3);
    *(float2*)(agg + (size_t)n * 256 + lane * 4) = u.f;
    if (lane < 4) {
        float dh = lane == 0 ? d0 : lane == 1 ? d1 : lane == 2 ? d2 : d3;
        salpha[(size_t)n * 4 + lane] = dh / (dh + EPS_SM);
    }
}

// ============================ post-aggregation projection ============================
// h[n][col] = relu( sum_j agg[n][j]*Wf[j][col] + sum_h salpha[n][h]*bpb[h*64+col]/4 + bias[col] ) + h_old
__global__ __launch_bounds__(256) void gemm2_kernel(const _Float16* __restrict__ agg,
                                                    const float* __restrict__ salpha,
                                                    const h2f* __restrict__ Wfh2,
                                                    const float* __restrict__ bpb,
                                                    const float* __restrict__ bias,
                                                    float* __restrict__ h, int N) {
    __shared__ _Float16 aggs[64 * 256];
    __shared__ float sals[64 * 4];
    int t = threadIdx.x;
    int col = t & 63, w = t >> 6;
    h2f wreg[128];
#pragma unroll
    for (int p = 0; p < 128; p++) wreg[p] = Wfh2[p * 64 + col];
    float bw0 = bpb[col] * 0.25f, bw1 = bpb[64 + col] * 0.25f;
    float bw2 = bpb[128 + col] * 0.25f, bw3 = bpb[192 + col] * 0.25f;
    float bcol = bias[col];
    int r0 = blockIdx.x * 64;
    const float4* ag = (const float4*)(agg + (size_t)r0 * 256);
    float4* as4 = (float4*)aggs;
    size_t tot = (size_t)N * 32;    // float4 count of agg
#pragma unroll
    for (int i = 0; i < 8; i++) {
        int idx = t + i * 256;
        size_t g = (size_t)r0 * 32 + idx;
        as4[idx] = (g < tot) ? ag[idx] : make_float4(0.f, 0.f, 0.f, 0.f);
    }
    if (t < 64) {
        size_t g = (size_t)r0 + t;
        float4 sv = (g < (size_t)N) ? ((const float4*)salpha)[g] : make_float4(0.f, 0.f, 0.f, 0.f);
        ((float4*)sals)[t] = sv;
    }
    __syncthreads();
    for (int rr = 0; rr < 16; rr++) {
        int r = w * 16 + rr;
        int rg = r0 + r;
        if (rg >= N) break;
        const float4* ar = (const float4*)(aggs + r * 256);
        float a0 = 0.f, a1 = 0.f, a2 = 0.f, a3 = 0.f;
#pragma unroll
        for (int q = 0; q < 32; q++) {
            union { float4 f; h2f hh[4]; } u;
            u.f = ar[q];
            a0 = DOT2(u.hh[0], wreg[4 * q + 0], a0);
            a1 = DOT2(u.hh[1], wreg[4 * q + 1], a1);
            a2 = DOT2(u.hh[2], wreg[4 * q + 2], a2);
            a3 = DOT2(u.hh[3], wreg[4 * q + 3], a3);
        }
        float acc = (a0 + a1) + (a2 + a3);
        const float* sr = sals + r * 4;
        acc += sr[0] * bw0 + sr[1] * bw1 + sr[2] * bw2 + sr[3] * bw3;
        size_t idx = (size_t)rg * 64 + col;
        float hv = h[idx];
        h[idx] = fmaxf(acc + bcol, 0.f) + hv;
    }
}

// ============================ pooling + FC head ============================
__global__ void pool_fc_kernel(const float* __restrict__ h, const int* __restrict__ gptr,
                               const float* __restrict__ fc1_w, const float* __restrict__ fc1_b,
                               const float* __restrict__ fc2_w, const float* __restrict__ fc2_b,
                               float* __restrict__ out, int G) {
    __shared__ float pool[4][64];
    int lane = threadIdx.x & 63, wv = threadIdx.x >> 6;
    int g = blockIdx.x * 4 + wv;
    float acc = 0.f;
    if (g < G) {
        int a = gptr[g], b = gptr[g + 1];
        for (int r = a; r < b; r++) acc += h[(size_t)r * 64 + lane];
    }
    pool[wv][lane] = acc;
    __syncthreads();
    float z1 = fc1_b[lane];
#pragma unroll 8
    for (int c = 0; c < 64; c++) z1 += pool[wv][c] * fc1_w[c * 64 + lane];
    z1 = fmaxf(z1, 0.f);
    float z2 = z1 * fc2_w[lane];
    z2 += __shfl_xor(z2, 1);
    z2 += __shfl_xor(z2, 2);
    z2 += __shfl_xor(z2, 4);
    z2 += __shfl_xor(z2, 8);
    z2 += __shfl_xor(z2, 16);
    z2 += __shfl_xor(z2, 32);
    if (g < G && lane == 0) out[g] = fmaxf(z2 + fc2_b[0], 0.f);
}

// ============================ host ============================
extern "C" void kernel_launch(void* const* d_in, const int* in_sizes, int n_in,
                              void* d_out, int out_size, void* d_ws, size_t ws_size,
                              hipStream_t stream) {
    const float* x         = (const float*)d_in[0];
    const int*   eindex    = (const int*)d_in[1];
    const float* edge_attr = (const float*)d_in[2];
    const int*   batch     = (const int*)d_in[3];
    const float* lin_w     = (const float*)d_in[4];
    const float* lin_b     = (const float*)d_in[5];
    const float* bn_gamma  = (const float*)d_in[6];
    const float* bn_beta   = (const float*)d_in[7];
    const float* conv_w    = (const float*)d_in[8];
    const float* conv_we   = (const float*)d_in[9];
    const float* att_src   = (const float*)d_in[10];
    const float* att_dst   = (const float*)d_in[11];
    const float* att_edge  = (const float*)d_in[12];
    const float* conv_bias = (const float*)d_in[13];
    const float* fc1_w     = (const float*)d_in[14];
    const float* fc1_b     = (const float*)d_in[15];
    const float* fc2_w     = (const float*)d_in[16];
    const float* fc2_b     = (const float*)d_in[17];
    float* out = (float*)d_out;

    int N = in_sizes[3];
    int E = in_sizes[1] / 2;
    int G = out_size;
    const int* esrc = eindex;
    const int* edst = eindex + E;

    char* wp = (char*)d_ws;
    auto carve = [&](size_t b) -> char* {
        char* p = wp;
        wp += (b + 511) & ~(size_t)511;
        return p;
    };
    float*     h      = (float*)carve((size_t)N * 64 * 4);      //  51.2 MB
    _Float16*  agg    = (_Float16*)carve((size_t)N * 256 * 2);  // 102.4 MB
    float*     salpha = (float*)carve((size_t)N * 4 * 4);       //   3.2 MB
    float*     a_sd   = (float*)carve((size_t)N * 8 * 4);       //   6.4 MB
    float*     a_e    = (float*)carve((size_t)E * 4 * 4);       //   6.4 MB
    int*       deg    = (int*)carve((size_t)N * 4);
    int*       row_ptr= (int*)carve((size_t)(N + 1) * 4);
    int*       cursor = (int*)carve((size_t)N * 4);
    int*       bsum   = (int*)carve(4096);
    int*       eid    = (int*)carve((size_t)E * 4);
    int*       gptr   = (int*)carve((size_t)(G + 1) * 4);
    float*     Wp     = (float*)carve(64 * 256 * 4);
    float*     bpb    = (float*)carve(256 * 4);
    float*     P      = (float*)carve(512 * 4);
    float*     cs     = (float*)carve(8 * 4);
    float*     Qm     = (float*)carve(32 * 4);
    h2f*       Wfh2   = (h2f*)carve(128 * 64 * 4);
    float*     bnacc  = (float*)carve(128 * 4);

    int nb1 = (N + 255) / 256;

    // CSR + graph ranges (static across layers)
    zero_kernel<<<nb1, 256, 0, stream>>>(deg, N);
    hist_kernel<<<(E + 255) / 256, 256, 0, stream>>>(edst, deg, E);
    scan1_kernel<<<nb1, 256, 0, stream>>>(deg, row_ptr, bsum, N);
    scan2_kernel<<<1, 1024, 0, stream>>>(bsum, nb1);
    scan3_kernel<<<(N + 1 + 255) / 256, 256, 0, stream>>>(row_ptr, cursor, bsum, N, E);
    scatter_kernel<<<(E + 255) / 256, 256, 0, stream>>>(edst, cursor, eid, E);
    gptr_kernel<<<(G + 1 + 255) / 256, 256, 0, stream>>>(batch, gptr, N, G);

    // input projection
    proj_kernel<<<(N + 63) / 64, 256, 0, stream>>>(x, lin_w, lin_b, h, N);

    for (int l = 0; l < 3; l++) {
        zero_kernel<<<1, 256, 0, stream>>>((int*)bnacc, 128);
        bn_stats_kernel<<<(N + 511) / 512, 256, 0, stream>>>(h, bnacc, N);
        fold_kernel<<<1, 256, 0, stream>>>(bnacc,
                                           bn_gamma + l * 64, bn_beta + l * 64,
                                           conv_w + (size_t)l * 64 * 256,
                                           conv_we + (size_t)l * 8 * 256,
                                           att_src + l * 256, att_dst + l * 256, att_edge + l * 256,
                                           Wp, bpb, P, cs, Qm, Wfh2, 1.f / (float)N);
        att_node_kernel<<<(N + 31) / 32, 256, 0, stream>>>(h, P, cs, a_sd, N);
        edge_score_kernel<<<(E + 255) / 256, 256, 0, stream>>>(edge_attr, Qm, a_e, E);
        edge_msg_kernel<<<(N + 3) / 4, 256, 0, stream>>>(row_ptr, eid, esrc, a_sd, a_e, h,
                                                         agg, salpha, N);
        gemm2_kernel<<<(N + 63) / 64, 256, 0, stream>>>(agg, salpha, Wfh2, bpb,
                                                        conv_bias + l * 64, h, N);
    }

    pool_fc_kernel<<<(G + 3) / 4, 256, 0, stream>>>(h, gptr, fc1_w, fc1_b, fc2_w, fc2_b, out, G);
}